// Round 1
// baseline (170.402 us; speedup 1.0000x reference)
//
#include <hip/hip_runtime.h>

// ---------------------------------------------------------------------------
// STRODE fused kernel for MI355X (gfx950)
//
// Structure per workgroup (256 thr = 4 waves, 32 batch rows, 20 Euler steps):
//   stage1 (transposed): H1^T[128u x 32b] = tanh(W1 * Y^T + b1)
//   stage2 (normal)    : H2[32b x 128u]   = tanh(H1 * W2^T + b2) * dt[b]
//   stage3 (transposed): Y  += W3 * H2^T + b3*dt   (MFMA accumulates into Y regs)
// All MFMA fragment reads are contiguous 16B; the single orientation flip is
// paid as 16 ds_write_b16/thread at stage-2 output. LDS tiles XOR-swizzled.
// ---------------------------------------------------------------------------

typedef __attribute__((ext_vector_type(8))) short s16x8;   // 8 x bf16 frag
typedef __attribute__((ext_vector_type(4))) float fx4;     // MFMA acc

#define NB   8192
#define DD   512
#define UU   100
#define UP   128
#define BM   32

__device__ __forceinline__ unsigned int f2bf(float x) {
  unsigned int u = __float_as_uint(x);
  return (u + 0x7FFFu + ((u >> 16) & 1u)) >> 16;   // RNE, no NaN inputs
}
__device__ __forceinline__ float bf2f(unsigned int h) {
  return __uint_as_float(h << 16);
}
__device__ __forceinline__ float tanh_fast(float x) {
  float e = __expf(2.0f * x);
  return 1.0f - 2.0f / (e + 1.0f);   // exact at +/-inf overflow, no NaN
}

// ---------------------------------------------------------------------------
// Weight prep: fp32 -> bf16, pad U=100 -> 128 with zeros.
//   ws[0      .. 65535 ] : W1b[128][512]  (rows >=100 zero)
//   ws[65536  .. 81919 ] : W2b[128][128]  (rows/cols >=100 zero)
//   ws[81920  .. 147455] : W3b[512][128]  (cols >=100 zero)
// ---------------------------------------------------------------------------
__global__ void prep_weights(const float* __restrict__ W1,
                             const float* __restrict__ W2,
                             const float* __restrict__ W3,
                             unsigned short* __restrict__ ws) {
  int e = blockIdx.x * 256 + threadIdx.x;
  if (e < 65536) {
    int u = e >> 9, kc = e & 511;
    ws[e] = (u < UU) ? (unsigned short)f2bf(W1[u * DD + kc]) : (unsigned short)0;
  } else if (e < 81920) {
    int e2 = e - 65536;
    int n = e2 >> 7, kc = e2 & 127;
    ws[e] = (n < UU && kc < UU) ? (unsigned short)f2bf(W2[n * UU + kc]) : (unsigned short)0;
  } else if (e < 147456) {
    int e3 = e - 81920;
    int d = e3 >> 7, kc = e3 & 127;
    ws[e] = (kc < UU) ? (unsigned short)f2bf(W3[d * UU + kc]) : (unsigned short)0;
  }
}

// ---------------------------------------------------------------------------
// Main fused ODE kernel. grid = 256 WGs x 256 thr, 32 rows/WG.
// ---------------------------------------------------------------------------
__global__ __launch_bounds__(256, 1) void ode_main(
    const float* __restrict__ y0, const float* __restrict__ t_seq,
    const float* __restrict__ b1, const float* __restrict__ b2,
    const float* __restrict__ b3,
    const unsigned short* __restrict__ W1b,
    const unsigned short* __restrict__ W2b,
    const unsigned short* __restrict__ W3b,
    const int* __restrict__ kptr, float* __restrict__ out) {
  __shared__ char Yb[BM * DD * 2];    // bf16 Y, row-major [32][512], swizzled
  __shared__ char H1s[BM * UP * 2];   // bf16 H1 [32][128], swizzled
  __shared__ char H2s[BM * UP * 2];   // bf16 H2*dt [32][128], swizzled

  const int tid  = threadIdx.x;
  const int w    = tid >> 6;
  const int lane = tid & 63;
  const int lo   = lane & 15;
  const int hi   = lane >> 4;
  const int b0   = blockIdx.x * BM;
  const int k    = *kptr;
  const float kinv = 1.0f / (float)k;

  // swizzle: XOR 16B-granule index with (row&7) -> conflict-free b128/b64/b16
  auto yboff = [](int b, int byr) -> int { return (b << 10) + (byr ^ ((b & 7) << 4)); };
  auto hoff  = [](int b, int byr) -> int { return (b << 8)  + (byr ^ ((b & 7) << 4)); };

  // ---- hoisted per-thread constants -------------------------------------
  float dt3[2];                       // dt for stage-1/3 fragment columns (b = j*16+lo)
#pragma unroll
  for (int j = 0; j < 2; ++j) {
    int b = b0 + j * 16 + lo;
    dt3[j] = (t_seq[2 * b + 1] - t_seq[2 * b]) * kinv;
  }
  float dtrow[2][4];                  // dt for stage-2 D rows (b = m*16+hi*4+r)
#pragma unroll
  for (int m = 0; m < 2; ++m)
#pragma unroll
    for (int r = 0; r < 4; ++r) {
      int b = b0 + m * 16 + hi * 4 + r;
      dtrow[m][r] = (t_seq[2 * b + 1] - t_seq[2 * b]) * kinv;
    }
  float b1v[2][4];
#pragma unroll
  for (int i = 0; i < 2; ++i)
#pragma unroll
    for (int r = 0; r < 4; ++r) {
      int u = (2 * w + i) * 16 + hi * 4 + r;
      b1v[i][r] = (u < UU) ? b1[u] : 0.0f;
    }
  float b2v[2];
#pragma unroll
  for (int j = 0; j < 2; ++j) {
    int u = (2 * w + j) * 16 + lo;
    b2v[j] = (u < UU) ? b2[u] : 0.0f;
  }
  float b3v[8][4];
#pragma unroll
  for (int i = 0; i < 8; ++i)
#pragma unroll
    for (int r = 0; r < 4; ++r) {
      int d = (8 * w + i) * 16 + hi * 4 + r;
      b3v[i][r] = b3[d];
    }

  // ---- persistent Y in registers (stage-3 D-fragment layout) ------------
  // Yr[i][j][r] = Y[row b = j*16+lo][col d = (8w+i)*16 + hi*4 + r]
  fx4 Yr[8][2];
#pragma unroll
  for (int i = 0; i < 8; ++i)
#pragma unroll
    for (int j = 0; j < 2; ++j) {
      const float* p = y0 + (size_t)(b0 + j * 16 + lo) * DD + (8 * w + i) * 16 + hi * 4;
      Yr[i][j] = *(const fx4*)p;
    }

  auto write_yb = [&]() {
#pragma unroll
    for (int i = 0; i < 8; ++i)
#pragma unroll
      for (int j = 0; j < 2; ++j) {
        int b   = j * 16 + lo;
        int byr = ((8 * w + i) * 16 + hi * 4) * 2;
        uint2 q;
        q.x = f2bf(Yr[i][j][0]) | (f2bf(Yr[i][j][1]) << 16);
        q.y = f2bf(Yr[i][j][2]) | (f2bf(Yr[i][j][3]) << 16);
        *(uint2*)(Yb + yboff(b, byr)) = q;
      }
  };
  write_yb();
  __syncthreads();

  const fx4 zf = {0.f, 0.f, 0.f, 0.f};

  for (int s = 0; s < k; ++s) {
    // ================= stage 1: H1^T = tanh(W1 * Y^T + b1) ===============
    // M = u (8 ut tiles, wave owns ut = 2w,2w+1), N = batch (2 bt), K = 512
    fx4 acc1[2][2];
#pragma unroll
    for (int i = 0; i < 2; ++i)
#pragma unroll
      for (int j = 0; j < 2; ++j) acc1[i][j] = zf;

    const unsigned short* a1p0 = W1b + ((2 * w + 0) * 16 + lo) * DD + hi * 8;
    const unsigned short* a1p1 = W1b + ((2 * w + 1) * 16 + lo) * DD + hi * 8;
#pragma unroll
    for (int kk = 0; kk < 16; ++kk) {
      s16x8 a0 = *(const s16x8*)(a1p0 + kk * 32);
      s16x8 a1 = *(const s16x8*)(a1p1 + kk * 32);
      int bro = kk * 64 + hi * 16;
      s16x8 bb0 = *(const s16x8*)(Yb + yboff(lo, bro));
      s16x8 bb1 = *(const s16x8*)(Yb + yboff(16 + lo, bro));
      acc1[0][0] = __builtin_amdgcn_mfma_f32_16x16x32_bf16(a0, bb0, acc1[0][0], 0, 0, 0);
      acc1[0][1] = __builtin_amdgcn_mfma_f32_16x16x32_bf16(a0, bb1, acc1[0][1], 0, 0, 0);
      acc1[1][0] = __builtin_amdgcn_mfma_f32_16x16x32_bf16(a1, bb0, acc1[1][0], 0, 0, 0);
      acc1[1][1] = __builtin_amdgcn_mfma_f32_16x16x32_bf16(a1, bb1, acc1[1][1], 0, 0, 0);
    }
    // D[u = ut*16+hi*4+r][b = bt*16+lo] -> H1[b][u..u+3] : contiguous b64
#pragma unroll
    for (int i = 0; i < 2; ++i)
#pragma unroll
      for (int j = 0; j < 2; ++j) {
        int b   = j * 16 + lo;
        int byr = ((2 * w + i) * 16 + hi * 4) * 2;
        uint2 q;
        q.x = f2bf(tanh_fast(acc1[i][j][0] + b1v[i][0])) |
              (f2bf(tanh_fast(acc1[i][j][1] + b1v[i][1])) << 16);
        q.y = f2bf(tanh_fast(acc1[i][j][2] + b1v[i][2])) |
              (f2bf(tanh_fast(acc1[i][j][3] + b1v[i][3])) << 16);
        *(uint2*)(H1s + hoff(b, byr)) = q;
      }
    __syncthreads();

    // ========= stage 2: H2 = tanh(H1 * W2^T + b2) * dt[b] ================
    // M = batch (2 mt), N = u (wave owns nt = 2w,2w+1), K = 128
    fx4 acc2[2][2];
#pragma unroll
    for (int i = 0; i < 2; ++i)
#pragma unroll
      for (int j = 0; j < 2; ++j) acc2[i][j] = zf;

    const unsigned short* b2p0 = W2b + ((2 * w + 0) * 16 + lo) * UP + hi * 8;
    const unsigned short* b2p1 = W2b + ((2 * w + 1) * 16 + lo) * UP + hi * 8;
#pragma unroll
    for (int kk = 0; kk < 4; ++kk) {
      int bro = kk * 64 + hi * 16;
      s16x8 am0 = *(const s16x8*)(H1s + hoff(lo, bro));
      s16x8 am1 = *(const s16x8*)(H1s + hoff(16 + lo, bro));
      s16x8 bn0 = *(const s16x8*)(b2p0 + kk * 32);
      s16x8 bn1 = *(const s16x8*)(b2p1 + kk * 32);
      acc2[0][0] = __builtin_amdgcn_mfma_f32_16x16x32_bf16(am0, bn0, acc2[0][0], 0, 0, 0);
      acc2[0][1] = __builtin_amdgcn_mfma_f32_16x16x32_bf16(am0, bn1, acc2[0][1], 0, 0, 0);
      acc2[1][0] = __builtin_amdgcn_mfma_f32_16x16x32_bf16(am1, bn0, acc2[1][0], 0, 0, 0);
      acc2[1][1] = __builtin_amdgcn_mfma_f32_16x16x32_bf16(am1, bn1, acc2[1][1], 0, 0, 0);
    }
    // D[b = m*16+hi*4+r][u = nt*16+lo]; fold dt here; scatter b16 (cheap: 16/thr)
#pragma unroll
    for (int m = 0; m < 2; ++m)
#pragma unroll
      for (int j = 0; j < 2; ++j) {
        int byr = ((2 * w + j) * 16 + lo) * 2;
#pragma unroll
        for (int r = 0; r < 4; ++r) {
          int b = m * 16 + hi * 4 + r;
          float hv = tanh_fast(acc2[m][j][r] + b2v[j]) * dtrow[m][r];
          *(unsigned short*)(H2s + hoff(b, byr)) = (unsigned short)f2bf(hv);
        }
      }
    __syncthreads();

    // ========= stage 3: Y += W3 * H2'^T + b3*dt  (acc straight into Yr) ==
    // M = d (wave owns mt = 8w..8w+7), N = batch (2 bt), K = 128
#pragma unroll
    for (int kk = 0; kk < 4; ++kk) {
      int bro = kk * 64 + hi * 16;
      s16x8 bb0 = *(const s16x8*)(H2s + hoff(lo, bro));
      s16x8 bb1 = *(const s16x8*)(H2s + hoff(16 + lo, bro));
#pragma unroll
      for (int i = 0; i < 8; ++i) {
        s16x8 a = *(const s16x8*)(W3b + ((8 * w + i) * 16 + lo) * UP + kk * 32 + hi * 8);
        Yr[i][0] = __builtin_amdgcn_mfma_f32_16x16x32_bf16(a, bb0, Yr[i][0], 0, 0, 0);
        Yr[i][1] = __builtin_amdgcn_mfma_f32_16x16x32_bf16(a, bb1, Yr[i][1], 0, 0, 0);
      }
    }
#pragma unroll
    for (int i = 0; i < 8; ++i)
#pragma unroll
      for (int j = 0; j < 2; ++j)
#pragma unroll
        for (int r = 0; r < 4; ++r) Yr[i][j][r] += b3v[i][r] * dt3[j];

    write_yb();
    __syncthreads();
  }

  // ---- final store: coalesced fp32 from bf16 Yb -------------------------
  for (int idx = tid; idx < BM * DD; idx += 256) {
    int b = idx >> 9, d = idx & 511;
    unsigned short h = *(const unsigned short*)(Yb + yboff(b, 2 * d));
    out[(size_t)(b0 + b) * 513 + d] = bf2f((unsigned int)h);
  }
}

// ---------------------------------------------------------------------------
// Loss column:  loss = ycum[-2] = 0.01 * sum_{t=1..98} gm_t   (exact algebra)
// ---------------------------------------------------------------------------
__global__ void loss_kernel(const float* __restrict__ bdp,
                            const float* __restrict__ sp,
                            const float* __restrict__ sdp,
                            float* __restrict__ out) {
  int b = blockIdx.x * 256 + threadIdx.x;
  if (b >= NB) return;
  float bd = bdp[b];
  float Kv = sp[b] + __logf(-bd + 0.01f) - __logf(sdp[b] + 0.01f);
  float acc = 0.0f;
  for (int t = 1; t <= 98; ++t) {
    float m = 0.01f * (float)t - 1.0f;     // in (-1, 0)
    float L = __logf(-m);                  // negative
    acc += (-bd) / (m * L) * (Kv - __logf(-L));
  }
  out[(size_t)b * 513 + 512] = 0.01f * acc;
}

// ---------------------------------------------------------------------------
extern "C" void kernel_launch(void* const* d_in, const int* in_sizes, int n_in,
                              void* d_out, int out_size, void* d_ws, size_t ws_size,
                              hipStream_t stream) {
  const float* y0    = (const float*)d_in[0];
  const float* t_seq = (const float*)d_in[1];
  const float* W1    = (const float*)d_in[2];
  const float* b1    = (const float*)d_in[3];
  const float* W2    = (const float*)d_in[4];
  const float* b2    = (const float*)d_in[5];
  const float* W3    = (const float*)d_in[6];
  const float* b3    = (const float*)d_in[7];
  const float* bd    = (const float*)d_in[9];
  const float* s_    = (const float*)d_in[10];
  const float* sd    = (const float*)d_in[11];
  const int*   kptr  = (const int*)d_in[12];
  float* out = (float*)d_out;
  unsigned short* ws = (unsigned short*)d_ws;

  prep_weights<<<576, 256, 0, stream>>>(W1, W2, W3, ws);
  ode_main<<<256, 256, 0, stream>>>(y0, t_seq, b1, b2, b3,
                                    ws, ws + 65536, ws + 81920, kptr, out);
  loss_kernel<<<32, 256, 0, stream>>>(bd, s_, sd, out);
}

// Round 2
// 143.240 us; speedup vs baseline: 1.1896x; 1.1896x over previous
//
#include <hip/hip_runtime.h>

// ---------------------------------------------------------------------------
// STRODE fused kernel for MI355X (gfx950) — round 2
//
// 256 WGs x 512 thr (8 waves), 32 batch rows/WG, 20 Euler steps.
// Weights preloaded ONCE into registers per wave (160 VGPR):
//   w1r: u-tile w of W1       (16 frags)   stage1: H1^T = tanh(W1 Y^T + b1)
//   w2r: n-tiles 2w&..  of W2 ( 8 frags)   stage2: H2 = tanh(H1 W2^T + b2)*dt
//   w3r: d-tiles 4w..   of W3 (16 frags)   stage3: Y += W3 H2^T + b3*dt
// Only activations round-trip through XOR-swizzled LDS.
// ---------------------------------------------------------------------------

typedef __attribute__((ext_vector_type(8))) short s16x8;   // 8 x bf16 frag
typedef __attribute__((ext_vector_type(4))) float fx4;     // MFMA acc

#define NB   8192
#define DD   512
#define UU   100
#define UP   128
#define BM   32

__device__ __forceinline__ unsigned int f2bf(float x) {
  unsigned int u = __float_as_uint(x);
  return (u + 0x7FFFu + ((u >> 16) & 1u)) >> 16;   // RNE, no NaN inputs
}
__device__ __forceinline__ float bf2f(unsigned int h) {
  return __uint_as_float(h << 16);
}
__device__ __forceinline__ float tanh_fast(float x) {
  float e = __expf(2.0f * x);
  return 1.0f - 2.0f / (e + 1.0f);
}

// ---------------------------------------------------------------------------
// Weight prep: fp32 -> bf16, pad U=100 -> 128 with zeros.
// ---------------------------------------------------------------------------
__global__ void prep_weights(const float* __restrict__ W1,
                             const float* __restrict__ W2,
                             const float* __restrict__ W3,
                             unsigned short* __restrict__ ws) {
  int e = blockIdx.x * 256 + threadIdx.x;
  if (e < 65536) {
    int u = e >> 9, kc = e & 511;
    ws[e] = (u < UU) ? (unsigned short)f2bf(W1[u * DD + kc]) : (unsigned short)0;
  } else if (e < 81920) {
    int e2 = e - 65536;
    int n = e2 >> 7, kc = e2 & 127;
    ws[e] = (n < UU && kc < UU) ? (unsigned short)f2bf(W2[n * UU + kc]) : (unsigned short)0;
  } else if (e < 147456) {
    int e3 = e - 81920;
    int d = e3 >> 7, kc = e3 & 127;
    ws[e] = (kc < UU) ? (unsigned short)f2bf(W3[d * UU + kc]) : (unsigned short)0;
  }
}

// ---------------------------------------------------------------------------
// Main fused ODE kernel. grid = 256 WGs x 512 thr, 32 rows/WG, 8 waves.
// ---------------------------------------------------------------------------
__global__ __launch_bounds__(512, 2) void ode_main(
    const float* __restrict__ y0, const float* __restrict__ t_seq,
    const float* __restrict__ b1, const float* __restrict__ b2,
    const float* __restrict__ b3,
    const unsigned short* __restrict__ W1b,
    const unsigned short* __restrict__ W2b,
    const unsigned short* __restrict__ W3b,
    const int* __restrict__ kptr, float* __restrict__ out) {
  __shared__ char Yb[BM * DD * 2];    // bf16 Y [32][512], swizzled
  __shared__ char H1s[BM * UP * 2];   // bf16 H1 [32][128], swizzled
  __shared__ char H2s[BM * UP * 2];   // bf16 H2*dt [32][128], swizzled

  const int tid  = threadIdx.x;
  const int w    = tid >> 6;          // wave 0..7
  const int lane = tid & 63;
  const int lo   = lane & 15;
  const int hi   = lane >> 4;
  const int b0   = blockIdx.x * BM;
  const int m2   = w >> 2;            // stage2 m-tile (batch half)
  const int n0   = 2 * (w & 3);       // stage2 first n-tile
  const int k    = *kptr;
  const float kinv = 1.0f / (float)k;

  auto yboff = [](int b, int byr) -> int { return (b << 10) + (byr ^ ((b & 7) << 4)); };
  auto hoff  = [](int b, int byr) -> int { return (b << 8)  + (byr ^ ((b & 7) << 4)); };

  // ---- register-resident weights (loaded once) --------------------------
  s16x8 w1r[16];                      // stage1 A: u-tile w, 16 k-chunks
#pragma unroll
  for (int kk = 0; kk < 16; ++kk)
    w1r[kk] = *(const s16x8*)(W1b + (w * 16 + lo) * DD + kk * 32 + hi * 8);
  s16x8 w2r[2][4];                    // stage2 B: n-tiles n0,n0+1
#pragma unroll
  for (int nj = 0; nj < 2; ++nj)
#pragma unroll
    for (int kk = 0; kk < 4; ++kk)
      w2r[nj][kk] = *(const s16x8*)(W2b + ((n0 + nj) * 16 + lo) * UP + kk * 32 + hi * 8);
  s16x8 w3r[4][4];                    // stage3 A: d-tiles 4w..4w+3
#pragma unroll
  for (int i = 0; i < 4; ++i)
#pragma unroll
    for (int kk = 0; kk < 4; ++kk)
      w3r[i][kk] = *(const s16x8*)(W3b + ((w * 4 + i) * 16 + lo) * UP + kk * 32 + hi * 8);

  // ---- hoisted per-thread constants -------------------------------------
  float b1v[4];                       // u = w*16 + hi*4 + r
#pragma unroll
  for (int r = 0; r < 4; ++r) {
    int u = w * 16 + hi * 4 + r;
    b1v[r] = (u < UU) ? b1[u] : 0.0f;
  }
  float b2v[2];                       // u = (n0+nj)*16 + lo
#pragma unroll
  for (int nj = 0; nj < 2; ++nj) {
    int u = (n0 + nj) * 16 + lo;
    b2v[nj] = (u < UU) ? b2[u] : 0.0f;
  }
  float dtrow[4];                     // stage2 rows: b = m2*16 + hi*4 + r
#pragma unroll
  for (int r = 0; r < 4; ++r) {
    int b = b0 + m2 * 16 + hi * 4 + r;
    dtrow[r] = (t_seq[2 * b + 1] - t_seq[2 * b]) * kinv;
  }
  float dt3[2];                       // stage3 cols: b = j*16 + lo
#pragma unroll
  for (int j = 0; j < 2; ++j) {
    int b = b0 + j * 16 + lo;
    dt3[j] = (t_seq[2 * b + 1] - t_seq[2 * b]) * kinv;
  }
  float b3v[4][4];                    // d = (w*4+i)*16 + hi*4 + r
#pragma unroll
  for (int i = 0; i < 4; ++i)
#pragma unroll
    for (int r = 0; r < 4; ++r)
      b3v[i][r] = b3[(w * 4 + i) * 16 + hi * 4 + r];

  // ---- persistent Y in registers (stage-3 D-fragment layout) ------------
  // Yr[i][j][r] = Y[b = j*16+lo][d = (4w+i)*16 + hi*4 + r]
  fx4 Yr[4][2];
#pragma unroll
  for (int i = 0; i < 4; ++i)
#pragma unroll
    for (int j = 0; j < 2; ++j) {
      const float* p = y0 + (size_t)(b0 + j * 16 + lo) * DD + (w * 4 + i) * 16 + hi * 4;
      Yr[i][j] = *(const fx4*)p;
    }

  auto write_yb = [&]() {
#pragma unroll
    for (int i = 0; i < 4; ++i)
#pragma unroll
      for (int j = 0; j < 2; ++j) {
        int b   = j * 16 + lo;
        int byr = ((w * 4 + i) * 16 + hi * 4) * 2;
        uint2 q;
        q.x = f2bf(Yr[i][j][0]) | (f2bf(Yr[i][j][1]) << 16);
        q.y = f2bf(Yr[i][j][2]) | (f2bf(Yr[i][j][3]) << 16);
        *(uint2*)(Yb + yboff(b, byr)) = q;
      }
  };
  write_yb();
  __syncthreads();

  const fx4 zf = {0.f, 0.f, 0.f, 0.f};

  for (int s = 0; s < k; ++s) {
    // ========= stage 1: H1^T[u-tile w][32b] = tanh(W1 Y^T + b1) ==========
    fx4 acc1[2];
    acc1[0] = zf; acc1[1] = zf;
#pragma unroll
    for (int kk = 0; kk < 16; ++kk) {
      int bro = kk * 64 + hi * 16;
      s16x8 bb0 = *(const s16x8*)(Yb + yboff(lo, bro));
      s16x8 bb1 = *(const s16x8*)(Yb + yboff(16 + lo, bro));
      acc1[0] = __builtin_amdgcn_mfma_f32_16x16x32_bf16(w1r[kk], bb0, acc1[0], 0, 0, 0);
      acc1[1] = __builtin_amdgcn_mfma_f32_16x16x32_bf16(w1r[kk], bb1, acc1[1], 0, 0, 0);
    }
#pragma unroll
    for (int j = 0; j < 2; ++j) {
      int b   = j * 16 + lo;
      int byr = (w * 16 + hi * 4) * 2;
      uint2 q;
      q.x = f2bf(tanh_fast(acc1[j][0] + b1v[0])) |
            (f2bf(tanh_fast(acc1[j][1] + b1v[1])) << 16);
      q.y = f2bf(tanh_fast(acc1[j][2] + b1v[2])) |
            (f2bf(tanh_fast(acc1[j][3] + b1v[3])) << 16);
      *(uint2*)(H1s + hoff(b, byr)) = q;
    }
    __syncthreads();

    // ========= stage 2: H2[m2][n0,n0+1] = tanh(H1 W2^T + b2) * dt ========
    fx4 acc2[2];
    acc2[0] = zf; acc2[1] = zf;
#pragma unroll
    for (int kk = 0; kk < 4; ++kk) {
      s16x8 am = *(const s16x8*)(H1s + hoff(m2 * 16 + lo, kk * 64 + hi * 16));
      acc2[0] = __builtin_amdgcn_mfma_f32_16x16x32_bf16(am, w2r[0][kk], acc2[0], 0, 0, 0);
      acc2[1] = __builtin_amdgcn_mfma_f32_16x16x32_bf16(am, w2r[1][kk], acc2[1], 0, 0, 0);
    }
#pragma unroll
    for (int nj = 0; nj < 2; ++nj) {
      int byr = ((n0 + nj) * 16 + lo) * 2;
#pragma unroll
      for (int r = 0; r < 4; ++r) {
        int b = m2 * 16 + hi * 4 + r;
        float hv = tanh_fast(acc2[nj][r] + b2v[nj]) * dtrow[r];
        *(unsigned short*)(H2s + hoff(b, byr)) = (unsigned short)f2bf(hv);
      }
    }
    __syncthreads();

    // ========= stage 3: Y += W3 H2'^T + b3*dt  (acc straight into Yr) ====
#pragma unroll
    for (int kk = 0; kk < 4; ++kk) {
      int bro = kk * 64 + hi * 16;
      s16x8 bb0 = *(const s16x8*)(H2s + hoff(lo, bro));
      s16x8 bb1 = *(const s16x8*)(H2s + hoff(16 + lo, bro));
#pragma unroll
      for (int i = 0; i < 4; ++i) {
        Yr[i][0] = __builtin_amdgcn_mfma_f32_16x16x32_bf16(w3r[i][kk], bb0, Yr[i][0], 0, 0, 0);
        Yr[i][1] = __builtin_amdgcn_mfma_f32_16x16x32_bf16(w3r[i][kk], bb1, Yr[i][1], 0, 0, 0);
      }
    }
#pragma unroll
    for (int i = 0; i < 4; ++i)
#pragma unroll
      for (int j = 0; j < 2; ++j)
#pragma unroll
        for (int r = 0; r < 4; ++r) Yr[i][j][r] += b3v[i][r] * dt3[j];

    write_yb();
    __syncthreads();
  }

  // ---- final store: coalesced fp32 from bf16 Yb -------------------------
  for (int idx = tid; idx < BM * DD; idx += 512) {
    int b = idx >> 9, d = idx & 511;
    unsigned short h = *(const unsigned short*)(Yb + yboff(b, 2 * d));
    out[(size_t)(b0 + b) * 513 + d] = bf2f((unsigned int)h);
  }
}

// ---------------------------------------------------------------------------
// Loss column:  loss = ycum[-2] = 0.01 * sum_{t=1..98} gm_t   (exact algebra)
// ---------------------------------------------------------------------------
__global__ void loss_kernel(const float* __restrict__ bdp,
                            const float* __restrict__ sp,
                            const float* __restrict__ sdp,
                            float* __restrict__ out) {
  int b = blockIdx.x * 256 + threadIdx.x;
  if (b >= NB) return;
  float bd = bdp[b];
  float Kv = sp[b] + __logf(-bd + 0.01f) - __logf(sdp[b] + 0.01f);
  float acc = 0.0f;
  for (int t = 1; t <= 98; ++t) {
    float m = 0.01f * (float)t - 1.0f;     // in (-1, 0)
    float L = __logf(-m);                  // negative
    acc += (-bd) / (m * L) * (Kv - __logf(-L));
  }
  out[(size_t)b * 513 + 512] = 0.01f * acc;
}

// ---------------------------------------------------------------------------
extern "C" void kernel_launch(void* const* d_in, const int* in_sizes, int n_in,
                              void* d_out, int out_size, void* d_ws, size_t ws_size,
                              hipStream_t stream) {
  const float* y0    = (const float*)d_in[0];
  const float* t_seq = (const float*)d_in[1];
  const float* W1    = (const float*)d_in[2];
  const float* b1    = (const float*)d_in[3];
  const float* W2    = (const float*)d_in[4];
  const float* b2    = (const float*)d_in[5];
  const float* W3    = (const float*)d_in[6];
  const float* b3    = (const float*)d_in[7];
  const float* bd    = (const float*)d_in[9];
  const float* s_    = (const float*)d_in[10];
  const float* sd    = (const float*)d_in[11];
  const int*   kptr  = (const int*)d_in[12];
  float* out = (float*)d_out;
  unsigned short* ws = (unsigned short*)d_ws;

  prep_weights<<<576, 256, 0, stream>>>(W1, W2, W3, ws);
  ode_main<<<256, 512, 0, stream>>>(y0, t_seq, b1, b2, b3,
                                    ws, ws + 65536, ws + 81920, kptr, out);
  loss_kernel<<<32, 256, 0, stream>>>(bd, s_, sd, out);
}